// Round 7
// baseline (74.893 us; speedup 1.0000x reference)
//
#include <hip/hip_runtime.h>
#include <cmath>

// out[b,o] = bias[o] + sum_i x[b,i] * (w[i,o] + (|w[i,o]|+1e-15)*noise[b,i,o])
// BS=64, IN_F=1024, OUT_F=1024. Memory-bound on the 256 MiB noise stream.
//
// R6: fused tail. Grid (ic=8, b=64) as before, but the LAST i-chunk block of
// each b (detected via agent-scope fetch_or on a per-b flag) immediately
// reduces that b's 8 partials + bias -> out. Partials are written with
// agent-scope relaxed atomic stores (write-through to LLC, cross-XCD visible
// without L2 writeback fences). A 1-wave init kernel zeroes the flags each
// call (handles the 0xAA d_ws poison deterministically).

constexpr int BS    = 64;
constexpr int IN_F  = 1024;
constexpr int OUT_F = 1024;
constexpr int ICH   = 8;             // i-chunks
constexpr int CHUNK = IN_F / ICH;    // 128

__global__ __launch_bounds__(64) void bridgeout_init_flags(unsigned int* __restrict__ flags) {
  flags[threadIdx.x] = 0u;
}

// ---- Kernel: partial sums + last-arriving block reduces its b ----
__global__ __launch_bounds__(256) void bridgeout_partial_fused(
    const float* __restrict__ x, const float* __restrict__ w,
    const float* __restrict__ bias, const float* __restrict__ noise,
    float* __restrict__ partials, unsigned int* __restrict__ flags,
    float* __restrict__ out) {
  const int ic = blockIdx.x;   // i-chunk
  const int b  = blockIdx.y;   // batch sample
  const int t  = threadIdx.x;
  const int o  = t << 2;       // 4 consecutive outputs per thread

  __shared__ float xs[CHUNK];
  __shared__ int sLast;
  if (t < CHUNK) xs[t] = x[b * IN_F + ic * CHUNK + t];
  __syncthreads();

  const float* wp = w + (size_t)(ic * CHUNK) * OUT_F + o;
  const float* np = noise + ((size_t)b * IN_F + (size_t)(ic * CHUNK)) * OUT_F + o;

  float ax = 0.f, ay = 0.f, az = 0.f, aw = 0.f;
#pragma unroll 4
  for (int i = 0; i < CHUNK; ++i) {
    const float xv = xs[i];
    const float4 w4 = *reinterpret_cast<const float4*>(wp);
    const float4 n4 = *reinterpret_cast<const float4*>(np);
    // w_noisy = w + (|w|+1e-15)*noise ; acc += x * w_noisy
    ax = fmaf(xv, fmaf(fabsf(w4.x) + 1e-15f, n4.x, w4.x), ax);
    ay = fmaf(xv, fmaf(fabsf(w4.y) + 1e-15f, n4.y, w4.y), ay);
    az = fmaf(xv, fmaf(fabsf(w4.z) + 1e-15f, n4.z, w4.z), az);
    aw = fmaf(xv, fmaf(fabsf(w4.w) + 1e-15f, n4.w, w4.w), aw);
    wp += OUT_F;
    np += OUT_F;
  }

  // Publish partial via agent-scope write-through stores (no L2 flush needed).
  float* p = partials + (size_t)(ic * BS + b) * OUT_F + o;
  __hip_atomic_store(&p[0], ax, __ATOMIC_RELAXED, __HIP_MEMORY_SCOPE_AGENT);
  __hip_atomic_store(&p[1], ay, __ATOMIC_RELAXED, __HIP_MEMORY_SCOPE_AGENT);
  __hip_atomic_store(&p[2], az, __ATOMIC_RELAXED, __HIP_MEMORY_SCOPE_AGENT);
  __hip_atomic_store(&p[3], aw, __ATOMIC_RELAXED, __HIP_MEMORY_SCOPE_AGENT);
  __syncthreads();   // all lanes' stores issued before the flag update

  if (t == 0) {
    const unsigned int bit = 1u << ic;
    const unsigned int old = __hip_atomic_fetch_or(&flags[b], bit, __ATOMIC_ACQ_REL,
                                                   __HIP_MEMORY_SCOPE_AGENT);
    sLast = ((old | bit) == 0xFFu) ? 1 : 0;
  }
  __syncthreads();

  if (sLast) {
    // This block is the 8th arrival for b: reduce all chunks (LLC-resident).
    float4 a;
    const float4 bi = *reinterpret_cast<const float4*>(bias + o);
    a.x = bi.x; a.y = bi.y; a.z = bi.z; a.w = bi.w;
#pragma unroll
    for (int c = 0; c < ICH; ++c) {
      const float* q = partials + (size_t)(c * BS + b) * OUT_F + o;
      a.x += __hip_atomic_load(&q[0], __ATOMIC_RELAXED, __HIP_MEMORY_SCOPE_AGENT);
      a.y += __hip_atomic_load(&q[1], __ATOMIC_RELAXED, __HIP_MEMORY_SCOPE_AGENT);
      a.z += __hip_atomic_load(&q[2], __ATOMIC_RELAXED, __HIP_MEMORY_SCOPE_AGENT);
      a.w += __hip_atomic_load(&q[3], __ATOMIC_RELAXED, __HIP_MEMORY_SCOPE_AGENT);
    }
    *reinterpret_cast<float4*>(out + (size_t)b * OUT_F + o) = a;
  }
}

// ---- Fallback: fused single-pass (grid = BS), used only if ws too small ----
__global__ __launch_bounds__(256) void bridgeout_fused(
    const float* __restrict__ x, const float* __restrict__ w,
    const float* __restrict__ bias, const float* __restrict__ noise,
    float* __restrict__ out) {
  const int b = blockIdx.x;
  const int t = threadIdx.x;
  const int o = t << 2;

  __shared__ float xs[IN_F];
  for (int i = t; i < IN_F; i += 256) xs[i] = x[b * IN_F + i];
  __syncthreads();

  const float* wp = w + o;
  const float* np = noise + (size_t)b * IN_F * OUT_F + o;
  float ax = 0.f, ay = 0.f, az = 0.f, aw = 0.f;
#pragma unroll 4
  for (int i = 0; i < IN_F; ++i) {
    const float xv = xs[i];
    const float4 w4 = *reinterpret_cast<const float4*>(wp);
    const float4 n4 = *reinterpret_cast<const float4*>(np);
    ax = fmaf(xv, fmaf(fabsf(w4.x) + 1e-15f, n4.x, w4.x), ax);
    ay = fmaf(xv, fmaf(fabsf(w4.y) + 1e-15f, n4.y, w4.y), ay);
    az = fmaf(xv, fmaf(fabsf(w4.z) + 1e-15f, n4.z, w4.z), az);
    aw = fmaf(xv, fmaf(fabsf(w4.w) + 1e-15f, n4.w, w4.w), aw);
    wp += OUT_F;
    np += OUT_F;
  }
  const float4 bi = *reinterpret_cast<const float4*>(bias + o);
  float4 acc = make_float4(ax + bi.x, ay + bi.y, az + bi.z, aw + bi.w);
  *reinterpret_cast<float4*>(out + (size_t)b * OUT_F + o) = acc;
}

extern "C" void kernel_launch(void* const* d_in, const int* in_sizes, int n_in,
                              void* d_out, int out_size, void* d_ws, size_t ws_size,
                              hipStream_t stream) {
  const float* x     = (const float*)d_in[0];
  const float* w     = (const float*)d_in[1];
  const float* bias  = (const float*)d_in[2];
  const float* noise = (const float*)d_in[3];
  float* out = (float*)d_out;

  const size_t partial_bytes = (size_t)ICH * BS * OUT_F * sizeof(float);  // 2 MiB
  const size_t need = partial_bytes + BS * sizeof(unsigned int);
  if (ws_size >= need) {
    float* partials = (float*)d_ws;
    unsigned int* flags = (unsigned int*)((char*)d_ws + partial_bytes);
    bridgeout_init_flags<<<1, 64, 0, stream>>>(flags);
    dim3 g1(ICH, BS);
    bridgeout_partial_fused<<<g1, 256, 0, stream>>>(x, w, bias, noise,
                                                    partials, flags, out);
  } else {
    bridgeout_fused<<<BS, 256, 0, stream>>>(x, w, bias, noise, out);
  }
}